// Round 10
// baseline (346.052 us; speedup 1.0000x reference)
//
#include <hip/hip_runtime.h>
#include <stdint.h>

#define N_IMG 256
#define HW 196
#define CDIM 512
#define NPT 13                       // 13 p-tiles of 16 rows (last: 4 valid)

#define F_EPS_POS 0.65f
#define F_EPS_NEG 0.40f
#define F_INV_TAU (1.0f/0.03f)
#define F_TEMP 0.07f

typedef __attribute__((ext_vector_type(8))) short bf16x8;
typedef __attribute__((ext_vector_type(8))) unsigned short u16x8;
typedef __attribute__((ext_vector_type(4))) float f32x4;

__device__ __forceinline__ unsigned short f2bf(float x){
    unsigned int u = __float_as_uint(x);
    u = (u + 0x7FFFu + ((u >> 16) & 1u)) >> 16;
    return (unsigned short)u;
}
__device__ __forceinline__ float sigm(float x){ return 1.0f/(1.0f + __expf(-x)); }

// ---------------- kernel 1: audio L2-normalize -> bf16 ----------------
__global__ void audio_norm_k(const float* __restrict__ audio,
                             unsigned short* __restrict__ abf){
    int k = blockIdx.x, t = threadIdx.x;
    __shared__ float red[256];
    float v0 = audio[k*CDIM + t];
    float v1 = audio[k*CDIM + t + 256];
    red[t] = v0*v0 + v1*v1;
    __syncthreads();
    for (int s = 128; s > 0; s >>= 1){
        if (t < s) red[t] += red[t+s];
        __syncthreads();
    }
    float rrt = 1.0f / sqrtf(red[0]);
    abf[k*CDIM + t]       = f2bf(v0*rrt);
    abf[k*CDIM + t + 256] = f2bf(v1*rrt);
}

// ---------------- kernel 2: ZERO-LDS main GEMM ----------------
// ROUND-10 ABLATION: every round-0..9 variant kept the LDS pipe on the
// critical path (ds_read per MFMA pair + staged ds_writes + shfl butterflies
// = ds_bpermute + 1.8-3.4M conflict cycles, all through ONE per-CU pipe
// shared by 8 waves, in barrier-separated phases). This kernel has NO
// __shared__ AT ALL: A-fragments are loaded global->VGPR at the exact
// per-lane fragment address (row = col lane, 32B/lane), converted in-VALU,
// fed to MFMA with B in regs. No barrier. The only cross-lane traffic is
// 2 shfl_xor for the row-norm and the final quad-reduce.
// grid = 13*256 flat (n = bid&255, pt = bid>>8), 512 thr (8 waves);
// wave w owns k-cols w*32..+31 (2 chains, B = 128 VGPR). Each wave loads
// the same 32KB A-tile (8x redundant, L1-served). ss is summed from exactly
// the elements the lane loads (quads partition the row; 2 shfl_xor finish).
// Dot-product c-order identical to all prior rounds; ss order differs
// (r8/r9 precedent: passed absmax 0.0). Partials per pt (disjoint,
// deterministic); pd_k sums the 13 partials.
__global__ __launch_bounds__(512) __attribute__((amdgpu_waves_per_eu(2)))
void main_k(const float* __restrict__ frame,
            const unsigned short* __restrict__ abf,
            float* __restrict__ np, float* __restrict__ dp,
            float* __restrict__ hnp, float* __restrict__ hdp){
    const int t    = threadIdx.x;
    const int n    = blockIdx.x & 255;
    const int pt   = blockIdx.x >> 8;        // 0..12
    const int lane = t & 63, wid = t >> 6;   // wid 0..7
    const int col  = lane & 15, quad = lane >> 4;
    const int kg0  = wid*32 + col;           // this wave's two k columns
    const int kg1  = kg0 + 16;

    // ---- B fragments in registers (2 x 16 x bf16x8 = 128 VGPRs) ----
    bf16x8 B0[16], B1[16];
    {
        const unsigned short* b0p = abf + (size_t)kg0*CDIM + quad*8;
        const unsigned short* b1p = abf + (size_t)kg1*CDIM + quad*8;
        #pragma unroll
        for (int j = 0; j < 16; ++j){
            B0[j] = *(const bf16x8*)(b0p + j*32);
            B1[j] = *(const bf16x8*)(b1p + j*32);
        }
    }
#define ANCH8(a,b,c,d,e,f,g,h) \
    asm volatile("" : "+v"(a),"+v"(b),"+v"(c),"+v"(d),"+v"(e),"+v"(f),"+v"(g),"+v"(h))
    ANCH8(B0[0],B0[1],B0[2],B0[3],B0[4],B0[5],B0[6],B0[7]);
    ANCH8(B0[8],B0[9],B0[10],B0[11],B0[12],B0[13],B0[14],B0[15]);
    ANCH8(B1[0],B1[1],B1[2],B1[3],B1[4],B1[5],B1[6],B1[7]);
    ANCH8(B1[8],B1[9],B1[10],B1[11],B1[12],B1[13],B1[14],B1[15]);
#undef ANCH8

    // per-lane A row: fragment layout row = col, c = quad*8 + j*32 .. +7
    int prow = pt*16 + col; if (prow > HW-1) prow = HW-1;   // clamp pad rows
    const float* arow = frame + ((size_t)n*HW + prow)*CDIM + quad*8;

    f32x4 acc0 = {0.f,0.f,0.f,0.f};
    f32x4 acc1 = {0.f,0.f,0.f,0.f};
    float ss = 0.f;

    // ---- fused load+convert+MFMA, batched by 4 j to bound live floats ----
    #pragma unroll
    for (int jb = 0; jb < 4; ++jb){
        float4 va[4], vb[4];
        #pragma unroll
        for (int jj = 0; jj < 4; ++jj){
            const float4* p = (const float4*)(arow + (jb*4 + jj)*32);
            va[jj] = p[0];
            vb[jj] = p[1];
        }
        #pragma unroll
        for (int jj = 0; jj < 4; ++jj){
            float4 a = va[jj], b = vb[jj];
            ss += a.x*a.x + a.y*a.y + a.z*a.z + a.w*a.w
                + b.x*b.x + b.y*b.y + b.z*b.z + b.w*b.w;
            union { u16x8 u; bf16x8 h; } cv;
            cv.u = (u16x8){ f2bf(a.x), f2bf(a.y), f2bf(a.z), f2bf(a.w),
                            f2bf(b.x), f2bf(b.y), f2bf(b.z), f2bf(b.w) };
            acc0 = __builtin_amdgcn_mfma_f32_16x16x32_bf16(cv.h, B0[jb*4+jj], acc0, 0, 0, 0);
            acc1 = __builtin_amdgcn_mfma_f32_16x16x32_bf16(cv.h, B1[jb*4+jj], acc1, 0, 0, 0);
        }
    }

    // ---- row rsqrt: quads partition the row's 512 c -> 2 shfl finish ----
    ss += __shfl_xor(ss, 16, 64);
    ss += __shfl_xor(ss, 32, 64);
    float rn = (ss > 0.f) ? (1.0f/sqrtf(ss)) : 0.f;   // valid for row = col

    // ---- epilogue: weighted reductions over this tile's valid rows ----
    float en0=0.f, en1=0.f, ed0=0.f, ed1=0.f;
    float hn0=0.f, hn1=0.f, hd0=0.f, hd1=0.f;
    #pragma unroll
    for (int rr = 0; rr < 4; ++rr){
        int row = quad*4 + rr;                // 0..15
        int pr  = pt*16 + row;
        float rnr = __shfl(rn, row, 64);      // rn lives in lane 'row'
        if (pr < HW){
            float s0 = acc0[rr] * rnr;
            float s1 = acc1[rr] * rnr;
            float w0 = sigm((s0 - F_EPS_POS) * F_INV_TAU);
            float w1 = sigm((s1 - F_EPS_POS) * F_INV_TAU);
            en0 += w0*s0; ed0 += w0;
            en1 += w1*s1; ed1 += w1;
            if (kg0 == n){ float wn = 1.f - sigm((s0 - F_EPS_NEG) * F_INV_TAU); hn0 += wn*s0; hd0 += wn; }
            if (kg1 == n){ float wn = 1.f - sigm((s1 - F_EPS_NEG) * F_INV_TAU); hn1 += wn*s1; hd1 += wn; }
        }
    }

    en0 += __shfl_xor(en0, 16, 64); en0 += __shfl_xor(en0, 32, 64);
    ed0 += __shfl_xor(ed0, 16, 64); ed0 += __shfl_xor(ed0, 32, 64);
    en1 += __shfl_xor(en1, 16, 64); en1 += __shfl_xor(en1, 32, 64);
    ed1 += __shfl_xor(ed1, 16, 64); ed1 += __shfl_xor(ed1, 32, 64);
    hn0 += __shfl_xor(hn0, 16, 64); hn0 += __shfl_xor(hn0, 32, 64);
    hd0 += __shfl_xor(hd0, 16, 64); hd0 += __shfl_xor(hd0, 32, 64);
    hn1 += __shfl_xor(hn1, 16, 64); hn1 += __shfl_xor(hn1, 32, 64);
    hd1 += __shfl_xor(hd1, 16, 64); hd1 += __shfl_xor(hd1, 32, 64);

    if (quad == 0){
        float* npp = np + (size_t)pt*N_IMG*N_IMG + n*N_IMG;
        float* dpp = dp + (size_t)pt*N_IMG*N_IMG + n*N_IMG;
        npp[kg0] = en0;  dpp[kg0] = ed0;
        npp[kg1] = en1;  dpp[kg1] = ed1;
        if (kg0 == n){ hnp[pt*N_IMG + n] = hn0; hdp[pt*N_IMG + n] = hd0; }
        if (kg1 == n){ hnp[pt*N_IMG + n] = hn1; hdp[pt*N_IMG + n] = hd1; }
    }
}

// ---------------- kernel 3: per-n Pi_d / Ni_d (sums the 13 p-tile partials) ----------------
__global__ void pd_k(const float* __restrict__ np, const float* __restrict__ dp,
                     const float* __restrict__ hnp, const float* __restrict__ hdp,
                     float* __restrict__ Pi_d, float* __restrict__ Ni_d){
    int nn = blockIdx.x, t = threadIdx.x;
    __shared__ float red[256];
    __shared__ float diagv;
    float nsum = 0.f, dsum = 0.f;
    #pragma unroll
    for (int ptile = 0; ptile < NPT; ++ptile){
        nsum += np[(size_t)ptile*N_IMG*N_IMG + nn*N_IMG + t];
        dsum += dp[(size_t)ptile*N_IMG*N_IMG + nn*N_IMG + t];
    }
    float ratio = nsum / dsum;
    if (t == nn) diagv = ratio;
    red[t] = ratio * (t == nn ? -99.f : 1.f);
    __syncthreads();
    for (int s = 128; s > 0; s >>= 1){
        if (t < s) red[t] += red[t+s];
        __syncthreads();
    }
    if (t == 0){
        float hn = 0.f, hd = 0.f;
        #pragma unroll
        for (int ptile = 0; ptile < NPT; ++ptile){
            hn += hnp[ptile*N_IMG + nn];
            hd += hdp[ptile*N_IMG + nn];
        }
        Pi_d[nn] = F_TEMP * diagv;
        Ni_d[nn] = F_TEMP * (hn/hd + red[0]);
    }
}

// ---------------- kernel 4: broadcast (N,N) log-sum + atomic total ----------------
__global__ void loss_k(const float* __restrict__ Pi_d, const float* __restrict__ Ni_d,
                       float* __restrict__ out){
    int i = blockIdx.x, j = threadIdx.x;
    __shared__ float red[256];
    float x = Ni_d[j] - Pi_d[i];
    red[j] = (x > 20.f) ? x : log1pf(__expf(x));
    __syncthreads();
    for (int s = 128; s > 0; s >>= 1){
        if (j < s) red[j] += red[j+s];
        __syncthreads();
    }
    if (j == 0) atomicAdd(out, red[0] * (1.0f/(float)N_IMG));
}

extern "C" void kernel_launch(void* const* d_in, const int* in_sizes, int n_in,
                              void* d_out, int out_size, void* d_ws, size_t ws_size,
                              hipStream_t stream) {
    const float* frame = (const float*)d_in[0];
    const float* audio = (const float*)d_in[1];
    float* out = (float*)d_out;
    char* ws = (char*)d_ws;

    unsigned short* abf = (unsigned short*)(ws);            // 262144 B
    float* np   = (float*)(ws + 262144);                    // 13*262144 = 3407872 B
    float* dp   = (float*)(ws + 3670016);                   // 3407872 B
    float* hnp  = (float*)(ws + 7077888);                   // 13312 B
    float* hdp  = (float*)(ws + 7091200);                   // 13312 B
    float* Pi_d = (float*)(ws + 7104512);                   // 1024 B
    float* Ni_d = (float*)(ws + 7105536);                   // 1024 B

    hipMemsetAsync(out, 0, sizeof(float), stream);          // capture-legal

    audio_norm_k<<<N_IMG, 256, 0, stream>>>(audio, abf);
    main_k<<<NPT*N_IMG, 512, 0, stream>>>(frame, abf, np, dp, hnp, hdp);
    pd_k<<<N_IMG, 256, 0, stream>>>(np, dp, hnp, hdp, Pi_d, Ni_d);
    loss_k<<<N_IMG, 256, 0, stream>>>(Pi_d, Ni_d, out);
}

// Round 11
// 219.050 us; speedup vs baseline: 1.5798x; 1.5798x over previous
//
#include <hip/hip_runtime.h>
#include <stdint.h>

#define N_IMG 256
#define HW 196
#define CDIM 512
#define NCH 16                        // 16 chunks of 32 channels
#define AROWS 208                     // 13 frags x 16 rows (196 valid)
#define LSTR 40                       // LDS row stride in elems: 80B, 16B-aligned b128

#define F_EPS_POS 0.65f
#define F_EPS_NEG 0.40f
#define F_INV_TAU (1.0f/0.03f)
#define F_TEMP 0.07f

typedef __attribute__((ext_vector_type(8))) short bf16x8;
typedef __attribute__((ext_vector_type(4))) float f32x4;

__device__ __forceinline__ unsigned short f2bf(float x){
    unsigned int u = __float_as_uint(x);
    u = (u + 0x7FFFu + ((u >> 16) & 1u)) >> 16;
    return (unsigned short)u;
}
__device__ __forceinline__ float sigm(float x){ return 1.0f/(1.0f + __expf(-x)); }

// ---------------- kernel 1: audio L2-normalize -> bf16 ----------------
__global__ void audio_norm_k(const float* __restrict__ audio,
                             unsigned short* __restrict__ abf){
    int k = blockIdx.x, t = threadIdx.x;
    __shared__ float red[256];
    float v0 = audio[k*CDIM + t];
    float v1 = audio[k*CDIM + t + 256];
    red[t] = v0*v0 + v1*v1;
    __syncthreads();
    for (int s = 128; s > 0; s >>= 1){
        if (t < s) red[t] += red[t+s];
        __syncthreads();
    }
    float rrt = 1.0f / sqrtf(red[0]);
    abf[k*CDIM + t]       = f2bf(v0*rrt);
    abf[k*CDIM + t + 256] = f2bf(v1*rrt);
}

// ---------------- kernel 2: main GEMM, m97-shape ----------------
// ROUND-11 ROOT CAUSE: in ALL prior rounds VGPR_Count < B-fragment demand
// (r10: 84 vs 128 even with asm anchors) -> the allocator never kept B
// resident; it sank the B GLOBAL loads into the MFMA chain (L2 ~200cy on
// every MFMA pair's dependence path). Latency-bound loop: every pipe <30%,
// invariant ~58us, insensitive to staging/barrier/occupancy changes.
// Fix = the proven m97 shape: BOTH operands read from LDS per MFMA; the
// only register-resident state is the accumulators (non-rematerializable).
// Loop over 16 c-chunks of 32: LDS dbuf A[208rows][32c] + B[256k][32c]
// (37KB/buf, 75KB total). Per wave per step: 13 A-reads + 2 B-reads (b128,
// stride-40 rows: 16B-aligned, bank-uniform) + 26 independent MFMAs into
// persistent acc0[13]/acc1[13]. Prefetch next chunk at step top (pinned by
// sched_barrier). c-order of every dot product identical to prior rounds
// (chunk == old j); ss summation order differs (r8-r10 precedent: passed).
__global__ __launch_bounds__(512)
void main_k(const float* __restrict__ frame,
            const unsigned short* __restrict__ abf,
            float* __restrict__ num, float* __restrict__ den,
            float* __restrict__ hnum, float* __restrict__ hden){
    __shared__ __align__(16) unsigned short Ash[2][AROWS*LSTR];
    __shared__ __align__(16) unsigned short Bsh[2][N_IMG*LSTR];
    __shared__ __align__(16) float rnS[AROWS];

    const int t    = threadIdx.x;
    const int n    = blockIdx.x;
    const int lane = t & 63, wid = t >> 6;   // wid 0..7
    const int col  = lane & 15, quad = lane >> 4;
    const int kg0  = wid*32 + col;           // this wave's two k columns
    const int kg1  = kg0 + 16;

    // staging identities
    const int rw = t >> 4;                   // A: row-within-32-group, 0..31
    const int c8 = t & 15;                   // A: float2 slot within 32c
    const int bk = t >> 1;                   // B: k row, 0..255
    const int bh = t & 1;                    // B: 16-elem half of 32c

    float  ss[7] = {0.f,0.f,0.f,0.f,0.f,0.f,0.f};
    float2 va[7];
    uint4  vb[2];

    auto loadC = [&](int ch){
        #pragma unroll
        for (int i = 0; i < 7; ++i){
            int row  = i*32 + rw;
            int prow = (row > HW-1) ? HW-1 : row;          // clamp pad rows
            va[i] = *(const float2*)(frame + ((size_t)n*HW + prow)*CDIM
                                     + ch*32 + c8*2);
        }
        const unsigned short* bp = abf + bk*CDIM + ch*32 + bh*16;
        vb[0] = *(const uint4*)(bp);
        vb[1] = *(const uint4*)(bp + 8);
    };
    auto storeC = [&](int buf){
        #pragma unroll
        for (int i = 0; i < 7; ++i){
            int row = i*32 + rw;
            if (row < AROWS){
                float x = va[i].x, y = va[i].y;
                if (row < HW) ss[i] += x*x + y*y;
                unsigned int pk = (unsigned int)f2bf(x)
                                | ((unsigned int)f2bf(y) << 16);
                *(unsigned int*)((char*)&Ash[buf][row*LSTR] + c8*4) = pk;
            }
        }
        *(uint4*)((char*)&Bsh[buf][bk*LSTR] + bh*32)      = vb[0];
        *(uint4*)((char*)&Bsh[buf][bk*LSTR] + bh*32 + 16) = vb[1];
    };

    f32x4 acc0[13], acc1[13];
    #pragma unroll
    for (int f = 0; f < 13; ++f){
        acc0[f] = (f32x4){0.f,0.f,0.f,0.f};
        acc1[f] = (f32x4){0.f,0.f,0.f,0.f};
    }

    // prologue: chunk 0 staged
    loadC(0); storeC(0);
    __syncthreads();

    for (int s = 0; s < NCH; ++s){
        if (s < NCH-1) loadC(s + 1);               // prefetch next chunk
        __builtin_amdgcn_sched_barrier(0);         // pin issue at step top
        const int cur = s & 1;
        // B fragments for this wave's two k-columns (from LDS, 2 reads)
        bf16x8 b0 = *(const bf16x8*)((char*)&Bsh[cur][(wid*32 + col)*LSTR] + quad*16);
        bf16x8 b1 = *(const bf16x8*)((char*)&Bsh[cur][(wid*32 + 16 + col)*LSTR] + quad*16);
        #pragma unroll
        for (int f = 0; f < 13; ++f){
            bf16x8 a = *(const bf16x8*)((char*)&Ash[cur][(f*16 + col)*LSTR] + quad*16);
            acc0[f] = __builtin_amdgcn_mfma_f32_16x16x32_bf16(a, b0, acc0[f], 0, 0, 0);
            acc1[f] = __builtin_amdgcn_mfma_f32_16x16x32_bf16(a, b1, acc1[f], 0, 0, 0);
        }
        if (s < NCH-1) storeC((s + 1) & 1);
        __syncthreads();
    }

    // ---- row rsqrt: reduce the 16 c8-threads of each row group ----
    if (t < AROWS - HW) rnS[HW + t] = 0.f;         // zero the pad-row slots
    #pragma unroll
    for (int i = 0; i < 7; ++i){
        float sv = ss[i];
        sv += __shfl_xor(sv, 1, 64);
        sv += __shfl_xor(sv, 2, 64);
        sv += __shfl_xor(sv, 4, 64);
        sv += __shfl_xor(sv, 8, 64);
        int row = i*32 + rw;
        if (c8 == 0 && row < HW)
            rnS[row] = (sv > 0.f) ? (1.0f/sqrtf(sv)) : 0.f;
    }
    __syncthreads();

    // ---- epilogue: weighted reductions ----
    float en0=0.f, en1=0.f, ed0=0.f, ed1=0.f;
    float hn0=0.f, hn1=0.f, hd0=0.f, hd1=0.f;
    #pragma unroll
    for (int f = 0; f < 13; ++f){
        f32x4 rn4 = *(const f32x4*)(&rnS[f*16 + quad*4]);
        #pragma unroll
        for (int rr = 0; rr < 4; ++rr){
            int pr = f*16 + quad*4 + rr;
            if (pr < HW){
                float s0 = acc0[f][rr] * rn4[rr];
                float s1 = acc1[f][rr] * rn4[rr];
                float w0 = sigm((s0 - F_EPS_POS) * F_INV_TAU);
                float w1 = sigm((s1 - F_EPS_POS) * F_INV_TAU);
                en0 += w0*s0; ed0 += w0;
                en1 += w1*s1; ed1 += w1;
                if (kg0 == n){ float wn = 1.f - sigm((s0 - F_EPS_NEG) * F_INV_TAU); hn0 += wn*s0; hd0 += wn; }
                if (kg1 == n){ float wn = 1.f - sigm((s1 - F_EPS_NEG) * F_INV_TAU); hn1 += wn*s1; hd1 += wn; }
            }
        }
    }

    en0 += __shfl_xor(en0, 16, 64); en0 += __shfl_xor(en0, 32, 64);
    ed0 += __shfl_xor(ed0, 16, 64); ed0 += __shfl_xor(ed0, 32, 64);
    en1 += __shfl_xor(en1, 16, 64); en1 += __shfl_xor(en1, 32, 64);
    ed1 += __shfl_xor(ed1, 16, 64); ed1 += __shfl_xor(ed1, 32, 64);
    hn0 += __shfl_xor(hn0, 16, 64); hn0 += __shfl_xor(hn0, 32, 64);
    hd0 += __shfl_xor(hd0, 16, 64); hd0 += __shfl_xor(hd0, 32, 64);
    hn1 += __shfl_xor(hn1, 16, 64); hn1 += __shfl_xor(hn1, 32, 64);
    hd1 += __shfl_xor(hd1, 16, 64); hd1 += __shfl_xor(hd1, 32, 64);

    if (quad == 0){
        num[n*N_IMG + kg0] = en0;  den[n*N_IMG + kg0] = ed0;
        num[n*N_IMG + kg1] = en1;  den[n*N_IMG + kg1] = ed1;
        if (kg0 == n){ hnum[n] = hn0; hden[n] = hd0; }
        if (kg1 == n){ hnum[n] = hn1; hden[n] = hd1; }
    }
}

// ---------------- kernel 3: per-n Pi_d / Ni_d ----------------
__global__ void pd_k(const float* __restrict__ num, const float* __restrict__ den,
                     const float* __restrict__ hnum, const float* __restrict__ hden,
                     float* __restrict__ Pi_d, float* __restrict__ Ni_d){
    int nn = blockIdx.x, t = threadIdx.x;
    __shared__ float red[256];
    __shared__ float diagv;
    float ratio = num[nn*N_IMG + t] / den[nn*N_IMG + t];
    if (t == nn) diagv = ratio;
    red[t] = ratio * (t == nn ? -99.f : 1.f);
    __syncthreads();
    for (int s = 128; s > 0; s >>= 1){
        if (t < s) red[t] += red[t+s];
        __syncthreads();
    }
    if (t == 0){
        Pi_d[nn] = F_TEMP * diagv;
        Ni_d[nn] = F_TEMP * (hnum[nn]/hden[nn] + red[0]);
    }
}

// ---------------- kernel 4: broadcast (N,N) log-sum + atomic total ----------------
__global__ void loss_k(const float* __restrict__ Pi_d, const float* __restrict__ Ni_d,
                       float* __restrict__ out){
    int i = blockIdx.x, j = threadIdx.x;
    __shared__ float red[256];
    float x = Ni_d[j] - Pi_d[i];
    red[j] = (x > 20.f) ? x : log1pf(__expf(x));
    __syncthreads();
    for (int s = 128; s > 0; s >>= 1){
        if (j < s) red[j] += red[j+s];
        __syncthreads();
    }
    if (j == 0) atomicAdd(out, red[0] * (1.0f/(float)N_IMG));
}

extern "C" void kernel_launch(void* const* d_in, const int* in_sizes, int n_in,
                              void* d_out, int out_size, void* d_ws, size_t ws_size,
                              hipStream_t stream) {
    const float* frame = (const float*)d_in[0];
    const float* audio = (const float*)d_in[1];
    float* out = (float*)d_out;
    char* ws = (char*)d_ws;

    unsigned short* abf = (unsigned short*)(ws);            // 262144 B
    float* num  = (float*)(ws + 262144);                    // 262144 B
    float* den  = (float*)(ws + 524288);                    // 262144 B
    float* hnum = (float*)(ws + 786432);                    // 1024 B
    float* hden = (float*)(ws + 787456);                    // 1024 B
    float* Pi_d = (float*)(ws + 788480);                    // 1024 B
    float* Ni_d = (float*)(ws + 789504);                    // 1024 B

    hipMemsetAsync(out, 0, sizeof(float), stream);          // capture-legal

    audio_norm_k<<<N_IMG, 256, 0, stream>>>(audio, abf);
    main_k<<<N_IMG, 512, 0, stream>>>(frame, abf, num, den, hnum, hden);
    pd_k<<<N_IMG, 256, 0, stream>>>(num, den, hnum, hden, Pi_d, Ni_d);
    loss_k<<<N_IMG, 256, 0, stream>>>(Pi_d, Ni_d, out);
}

// Round 12
// 218.447 us; speedup vs baseline: 1.5841x; 1.0028x over previous
//
#include <hip/hip_runtime.h>
#include <stdint.h>

#define N_IMG 256
#define HW 196
#define CDIM 512

#define F_EPS_POS 0.65f
#define F_EPS_NEG 0.40f
#define F_INV_TAU (1.0f/0.03f)
#define F_TEMP 0.07f

typedef __attribute__((ext_vector_type(8))) short bf16x8;
typedef __attribute__((ext_vector_type(4))) unsigned short u16x4;
typedef __attribute__((ext_vector_type(4))) float f32x4;

__device__ __forceinline__ unsigned short f2bf(float x){
    unsigned int u = __float_as_uint(x);
    u = (u + 0x7FFFu + ((u >> 16) & 1u)) >> 16;
    return (unsigned short)u;
}
__device__ __forceinline__ float sigm(float x){ return 1.0f/(1.0f + __expf(-x)); }

// ---------------- kernel 1: audio L2-normalize -> bf16 ----------------
__global__ void audio_norm_k(const float* __restrict__ audio,
                             unsigned short* __restrict__ abf){
    int k = blockIdx.x, t = threadIdx.x;
    __shared__ float red[256];
    float v0 = audio[k*CDIM + t];
    float v1 = audio[k*CDIM + t + 256];
    red[t] = v0*v0 + v1*v1;
    __syncthreads();
    for (int s = 128; s > 0; s >>= 1){
        if (t < s) red[t] += red[t+s];
        __syncthreads();
    }
    float rrt = 1.0f / sqrtf(red[0]);
    abf[k*CDIM + t]       = f2bf(v0*rrt);
    abf[k*CDIM + t + 256] = f2bf(v1*rrt);
}

// ---------------- kernel 2: main GEMM + weighted reductions ----------------
// Best-measured configuration (round 7, 174.1us total). 13 structural
// variants on both sides of this shape all landed at >= this time; the
// binding resource is not identifiable from available counters (all pipes
// <30%, insensitive to staging/occupancy/traffic/barrier changes). Kept
// byte-identical.
__global__ __launch_bounds__(512) __attribute__((amdgpu_waves_per_eu(2, 2)))
void main_k(const float* __restrict__ frame,
            const unsigned short* __restrict__ abf,
            float* __restrict__ num, float* __restrict__ den,
            float* __restrict__ hnum, float* __restrict__ hden){
    __shared__ unsigned short fT[2][16*520];   // 520 stride: conflict-free b128
    __shared__ float rnormS[2][16];

    const int t    = threadIdx.x;
    const int n    = blockIdx.x;
    const int lane = t & 63, wid = t >> 6;     // wid 0..7
    const int col  = lane & 15, quad = lane >> 4;
    const int kg0  = wid*32 + col;             // this wave's k columns
    const int kg1  = kg0 + 16;

    // ---- B fragments in registers (2 x 16 x bf16x8) ----
    bf16x8 B0[16], B1[16];
    {
        const unsigned short* b0p = abf + (size_t)kg0*CDIM + quad*8;
        const unsigned short* b1p = abf + (size_t)kg1*CDIM + quad*8;
        #pragma unroll
        for (int j = 0; j < 16; ++j){
            B0[j] = *(const bf16x8*)(b0p + j*32);
            B1[j] = *(const bf16x8*)(b1p + j*32);
        }
    }
#define ANCH8(a,b,c,d,e,f,g,h) \
    asm volatile("" : "+v"(a),"+v"(b),"+v"(c),"+v"(d),"+v"(e),"+v"(f),"+v"(g),"+v"(h))
    ANCH8(B0[0],B0[1],B0[2],B0[3],B0[4],B0[5],B0[6],B0[7]);
    ANCH8(B0[8],B0[9],B0[10],B0[11],B0[12],B0[13],B0[14],B0[15]);
    ANCH8(B1[0],B1[1],B1[2],B1[3],B1[4],B1[5],B1[6],B1[7]);
    ANCH8(B1[8],B1[9],B1[10],B1[11],B1[12],B1[13],B1[14],B1[15]);
#undef ANCH8

    const int r0 = 2*wid, r1 = r0 + 1;         // this wave's tile rows

    float en0=0.f, en1=0.f, ed0=0.f, ed1=0.f;
    float hn0=0.f, hn1=0.f, hd0=0.f, hd1=0.f;

    const float4* fbase_g = (const float4*)(frame + (size_t)n*HW*CDIM);

    // perfectly coalesced stage loads: each instr = 64 lanes x 16B contiguous
    auto loadT = [&](int pt, float4* v){
        int p0 = pt*16 + r0; if (p0 > HW-1) p0 = HW-1;   // clamped pad rows dup
        int p1 = pt*16 + r1; if (p1 > HW-1) p1 = HW-1;   // row 195; discarded
        const float4* s0 = fbase_g + (size_t)p0*(CDIM/4);
        const float4* s1 = fbase_g + (size_t)p1*(CDIM/4);
        v[0] = s0[lane]; v[1] = s0[lane + 64];
        v[2] = s1[lane]; v[3] = s1[lane + 64];
    };
    // convert+write rows into buf, full-wave row rsqrt via butterfly shuffle
    auto storeT = [&](const float4* v, int buf){
        float ss0 = v[0].x*v[0].x + v[0].y*v[0].y + v[0].z*v[0].z + v[0].w*v[0].w
                  + v[1].x*v[1].x + v[1].y*v[1].y + v[1].z*v[1].z + v[1].w*v[1].w;
        float ss1 = v[2].x*v[2].x + v[2].y*v[2].y + v[2].z*v[2].z + v[2].w*v[2].w
                  + v[3].x*v[3].x + v[3].y*v[3].y + v[3].z*v[3].z + v[3].w*v[3].w;
        unsigned short* d0 = fT[buf] + r0*520;
        unsigned short* d1 = fT[buf] + r1*520;
        u16x4 u0 = { f2bf(v[0].x), f2bf(v[0].y), f2bf(v[0].z), f2bf(v[0].w) };
        u16x4 u1 = { f2bf(v[1].x), f2bf(v[1].y), f2bf(v[1].z), f2bf(v[1].w) };
        u16x4 u2 = { f2bf(v[2].x), f2bf(v[2].y), f2bf(v[2].z), f2bf(v[2].w) };
        u16x4 u3 = { f2bf(v[3].x), f2bf(v[3].y), f2bf(v[3].z), f2bf(v[3].w) };
        *(u16x4*)(d0 + lane*4)       = u0;
        *(u16x4*)(d0 + 256 + lane*4) = u1;
        *(u16x4*)(d1 + lane*4)       = u2;
        *(u16x4*)(d1 + 256 + lane*4) = u3;
        #pragma unroll
        for (int dd = 1; dd < 64; dd <<= 1){
            ss0 += __shfl_xor(ss0, dd, 64);
            ss1 += __shfl_xor(ss1, dd, 64);
        }
        if (lane == 0){
            rnormS[buf][r0] = (ss0 > 0.f) ? (1.0f/sqrtf(ss0)) : 0.f;
            rnormS[buf][r1] = (ss1 > 0.f) ? (1.0f/sqrtf(ss1)) : 0.f;
        }
    };

    // prologue: tile 0 into buffer 0
    {
        float4 v[4];
        loadT(0, v);
        storeT(v, 0);
    }
    __syncthreads();

    for (int pt = 0; pt < 13; ++pt){
        const int cur = pt & 1, nxt = cur ^ 1;
        const bool hasNext = (pt < 12);

        float4 v[4];
        if (hasNext) loadT(pt + 1, v);   // prefetch: in flight under MFMA phase

        // ---- MFMA phase on buf[cur]: 16 ds_read shared by 2 MFMA chains ----
        const unsigned short* fbase = fT[cur] + col*520 + quad*8;
        f32x4 acc0 = {0.f,0.f,0.f,0.f};
        f32x4 acc1 = {0.f,0.f,0.f,0.f};
        #pragma unroll
        for (int j = 0; j < 16; ++j){
            bf16x8 a = *(const bf16x8*)(fbase + j*32);
            acc0 = __builtin_amdgcn_mfma_f32_16x16x32_bf16(a, B0[j], acc0, 0, 0, 0);
            acc1 = __builtin_amdgcn_mfma_f32_16x16x32_bf16(a, B1[j], acc1, 0, 0, 0);
        }
        f32x4 rn4 = *(const f32x4*)(&rnormS[cur][quad*4]);
        #pragma unroll
        for (int rr = 0; rr < 4; ++rr){
            int prow = pt*16 + quad*4 + rr;
            if (prow < HW){
                float s0 = acc0[rr] * rn4[rr];
                float s1 = acc1[rr] * rn4[rr];
                float w0 = sigm((s0 - F_EPS_POS) * F_INV_TAU);
                float w1 = sigm((s1 - F_EPS_POS) * F_INV_TAU);
                en0 += w0*s0; ed0 += w0;
                en1 += w1*s1; ed1 += w1;
                if (kg0 == n){ float wn = 1.f - sigm((s0 - F_EPS_NEG) * F_INV_TAU); hn0 += wn*s0; hd0 += wn; }
                if (kg1 == n){ float wn = 1.f - sigm((s1 - F_EPS_NEG) * F_INV_TAU); hn1 += wn*s1; hd1 += wn; }
            }
        }

        if (hasNext) storeT(v, nxt);
        __syncthreads();
    }

    // reduce across quads (rows live in quads; k identical per quad)
    en0 += __shfl_xor(en0, 16, 64); en0 += __shfl_xor(en0, 32, 64);
    ed0 += __shfl_xor(ed0, 16, 64); ed0 += __shfl_xor(ed0, 32, 64);
    en1 += __shfl_xor(en1, 16, 64); en1 += __shfl_xor(en1, 32, 64);
    ed1 += __shfl_xor(ed1, 16, 64); ed1 += __shfl_xor(ed1, 32, 64);
    hn0 += __shfl_xor(hn0, 16, 64); hn0 += __shfl_xor(hn0, 32, 64);
    hd0 += __shfl_xor(hd0, 16, 64); hd0 += __shfl_xor(hd0, 32, 64);
    hn1 += __shfl_xor(hn1, 16, 64); hn1 += __shfl_xor(hn1, 32, 64);
    hd1 += __shfl_xor(hd1, 16, 64); hd1 += __shfl_xor(hd1, 32, 64);

    if (quad == 0){
        num[n*N_IMG + kg0] = en0;  den[n*N_IMG + kg0] = ed0;
        num[n*N_IMG + kg1] = en1;  den[n*N_IMG + kg1] = ed1;
        if (kg0 == n){ hnum[n] = hn0; hden[n] = hd0; }
        if (kg1 == n){ hnum[n] = hn1; hden[n] = hd1; }
    }
}

// ---------------- kernel 3: per-n Pi_d / Ni_d (parallel over n) ----------------
__global__ void pd_k(const float* __restrict__ num, const float* __restrict__ den,
                     const float* __restrict__ hnum, const float* __restrict__ hden,
                     float* __restrict__ Pi_d, float* __restrict__ Ni_d){
    int nn = blockIdx.x, t = threadIdx.x;
    __shared__ float red[256];
    __shared__ float diagv;
    float ratio = num[nn*N_IMG + t] / den[nn*N_IMG + t];
    if (t == nn) diagv = ratio;
    red[t] = ratio * (t == nn ? -99.f : 1.f);
    __syncthreads();
    for (int s = 128; s > 0; s >>= 1){
        if (t < s) red[t] += red[t+s];
        __syncthreads();
    }
    if (t == 0){
        Pi_d[nn] = F_TEMP * diagv;
        Ni_d[nn] = F_TEMP * (hnum[nn]/hden[nn] + red[0]);
    }
}

// ---------------- kernel 4: single-block loss (no atomic, no memset) ----------------
// loss = (1/N) * sum_{i,j} log(1 + exp(Ni_d[j] - Pi_d[i]))
// ROUND-12 CHANGE: grid=1, 1024 threads. Thread t owns (j = t&255,
// i-quarter = t>>8): 64 i-iterations reading Pi from LDS (broadcast).
// Single block -> writes out[0] directly, removing the hipMemsetAsync
// dispatch and the 256-way atomic. Summation order per (i,j) term is a
// pure re-association (r8-r10 precedent: tolerance-robust).
__global__ __launch_bounds__(1024)
void loss_k(const float* __restrict__ Pi_d, const float* __restrict__ Ni_d,
            float* __restrict__ out){
    const int t = threadIdx.x;
    const int j = t & 255;
    const int iq = t >> 8;                 // 0..3
    __shared__ float PiS[256];
    __shared__ float red[1024];
    if (t < 256) PiS[t] = Pi_d[t];
    __syncthreads();
    float nj = Ni_d[j];
    float acc = 0.f;
    #pragma unroll 8
    for (int ii = 0; ii < 64; ++ii){
        float x = nj - PiS[iq*64 + ii];
        acc += (x > 20.f) ? x : log1pf(__expf(x));
    }
    red[t] = acc;
    __syncthreads();
    for (int s = 512; s > 0; s >>= 1){
        if (t < s) red[t] += red[t+s];
        __syncthreads();
    }
    if (t == 0) out[0] = red[0] * (1.0f/(float)N_IMG);
}

extern "C" void kernel_launch(void* const* d_in, const int* in_sizes, int n_in,
                              void* d_out, int out_size, void* d_ws, size_t ws_size,
                              hipStream_t stream) {
    const float* frame = (const float*)d_in[0];
    const float* audio = (const float*)d_in[1];
    float* out = (float*)d_out;
    char* ws = (char*)d_ws;

    unsigned short* abf = (unsigned short*)(ws);            // 262144 B
    float* num  = (float*)(ws + 262144);                    // 262144 B
    float* den  = (float*)(ws + 524288);                    // 262144 B
    float* hnum = (float*)(ws + 786432);                    // 1024 B
    float* hden = (float*)(ws + 787456);                    // 1024 B
    float* Pi_d = (float*)(ws + 788480);                    // 1024 B
    float* Ni_d = (float*)(ws + 789504);                    // 1024 B

    audio_norm_k<<<N_IMG, 256, 0, stream>>>(audio, abf);
    main_k<<<N_IMG, 512, 0, stream>>>(frame, abf, num, den, hnum, hden);
    pd_k<<<N_IMG, 256, 0, stream>>>(num, den, hnum, hden, Pi_d, Ni_d);
    loss_k<<<1, 1024, 0, stream>>>(Pi_d, Ni_d, out);
}

// Round 13
// 174.801 us; speedup vs baseline: 1.9797x; 1.2497x over previous
//
#include <hip/hip_runtime.h>
#include <stdint.h>

#define N_IMG 256
#define HW 196
#define CDIM 512

#define F_EPS_POS 0.65f
#define F_EPS_NEG 0.40f
#define F_INV_TAU (1.0f/0.03f)
#define F_TEMP 0.07f

typedef __attribute__((ext_vector_type(8))) short bf16x8;
typedef __attribute__((ext_vector_type(4))) unsigned short u16x4;
typedef __attribute__((ext_vector_type(4))) float f32x4;

__device__ __forceinline__ unsigned short f2bf(float x){
    unsigned int u = __float_as_uint(x);
    u = (u + 0x7FFFu + ((u >> 16) & 1u)) >> 16;
    return (unsigned short)u;
}
__device__ __forceinline__ float sigm(float x){ return 1.0f/(1.0f + __expf(-x)); }

// ---------------- kernel 1: audio L2-normalize -> bf16 ----------------
__global__ void audio_norm_k(const float* __restrict__ audio,
                             unsigned short* __restrict__ abf){
    int k = blockIdx.x, t = threadIdx.x;
    __shared__ float red[256];
    float v0 = audio[k*CDIM + t];
    float v1 = audio[k*CDIM + t + 256];
    red[t] = v0*v0 + v1*v1;
    __syncthreads();
    for (int s = 128; s > 0; s >>= 1){
        if (t < s) red[t] += red[t+s];
        __syncthreads();
    }
    float rrt = 1.0f / sqrtf(red[0]);
    abf[k*CDIM + t]       = f2bf(v0*rrt);
    abf[k*CDIM + t + 256] = f2bf(v1*rrt);
}

// ---------------- kernel 2: main GEMM + weighted reductions ----------------
// Best-measured configuration (174.1us total, round 7). Session ledger:
// 13 structural variants bracket this shape on every axis (k-split both
// directions, wave count 4/8/16, barrier discipline, gload_lds, zero-LDS,
// LDS-B, step count 8/13, flattened grid) -- all measured >= this. Its
// limiter is not identifiable from available counters (all pipes <30%,
// invariant under every mechanism-level intervention). Cross-round noise
// is +-25% (r12 = this main_k + less work measured +44us), so this kernel
// is locked as the session optimum. Kept byte-identical to round 7.
__global__ __launch_bounds__(512) __attribute__((amdgpu_waves_per_eu(2, 2)))
void main_k(const float* __restrict__ frame,
            const unsigned short* __restrict__ abf,
            float* __restrict__ num, float* __restrict__ den,
            float* __restrict__ hnum, float* __restrict__ hden){
    __shared__ unsigned short fT[2][16*520];   // 520 stride: conflict-free b128
    __shared__ float rnormS[2][16];

    const int t    = threadIdx.x;
    const int n    = blockIdx.x;
    const int lane = t & 63, wid = t >> 6;     // wid 0..7
    const int col  = lane & 15, quad = lane >> 4;
    const int kg0  = wid*32 + col;             // this wave's k columns
    const int kg1  = kg0 + 16;

    // ---- B fragments in registers (2 x 16 x bf16x8) ----
    bf16x8 B0[16], B1[16];
    {
        const unsigned short* b0p = abf + (size_t)kg0*CDIM + quad*8;
        const unsigned short* b1p = abf + (size_t)kg1*CDIM + quad*8;
        #pragma unroll
        for (int j = 0; j < 16; ++j){
            B0[j] = *(const bf16x8*)(b0p + j*32);
            B1[j] = *(const bf16x8*)(b1p + j*32);
        }
    }
#define ANCH8(a,b,c,d,e,f,g,h) \
    asm volatile("" : "+v"(a),"+v"(b),"+v"(c),"+v"(d),"+v"(e),"+v"(f),"+v"(g),"+v"(h))
    ANCH8(B0[0],B0[1],B0[2],B0[3],B0[4],B0[5],B0[6],B0[7]);
    ANCH8(B0[8],B0[9],B0[10],B0[11],B0[12],B0[13],B0[14],B0[15]);
    ANCH8(B1[0],B1[1],B1[2],B1[3],B1[4],B1[5],B1[6],B1[7]);
    ANCH8(B1[8],B1[9],B1[10],B1[11],B1[12],B1[13],B1[14],B1[15]);
#undef ANCH8

    const int r0 = 2*wid, r1 = r0 + 1;         // this wave's tile rows

    float en0=0.f, en1=0.f, ed0=0.f, ed1=0.f;
    float hn0=0.f, hn1=0.f, hd0=0.f, hd1=0.f;

    const float4* fbase_g = (const float4*)(frame + (size_t)n*HW*CDIM);

    // perfectly coalesced stage loads: each instr = 64 lanes x 16B contiguous
    auto loadT = [&](int pt, float4* v){
        int p0 = pt*16 + r0; if (p0 > HW-1) p0 = HW-1;   // clamped pad rows dup
        int p1 = pt*16 + r1; if (p1 > HW-1) p1 = HW-1;   // row 195; discarded
        const float4* s0 = fbase_g + (size_t)p0*(CDIM/4);
        const float4* s1 = fbase_g + (size_t)p1*(CDIM/4);
        v[0] = s0[lane]; v[1] = s0[lane + 64];
        v[2] = s1[lane]; v[3] = s1[lane + 64];
    };
    // convert+write rows into buf, full-wave row rsqrt via butterfly shuffle
    auto storeT = [&](const float4* v, int buf){
        float ss0 = v[0].x*v[0].x + v[0].y*v[0].y + v[0].z*v[0].z + v[0].w*v[0].w
                  + v[1].x*v[1].x + v[1].y*v[1].y + v[1].z*v[1].z + v[1].w*v[1].w;
        float ss1 = v[2].x*v[2].x + v[2].y*v[2].y + v[2].z*v[2].z + v[2].w*v[2].w
                  + v[3].x*v[3].x + v[3].y*v[3].y + v[3].z*v[3].z + v[3].w*v[3].w;
        unsigned short* d0 = fT[buf] + r0*520;
        unsigned short* d1 = fT[buf] + r1*520;
        u16x4 u0 = { f2bf(v[0].x), f2bf(v[0].y), f2bf(v[0].z), f2bf(v[0].w) };
        u16x4 u1 = { f2bf(v[1].x), f2bf(v[1].y), f2bf(v[1].z), f2bf(v[1].w) };
        u16x4 u2 = { f2bf(v[2].x), f2bf(v[2].y), f2bf(v[2].z), f2bf(v[2].w) };
        u16x4 u3 = { f2bf(v[3].x), f2bf(v[3].y), f2bf(v[3].z), f2bf(v[3].w) };
        *(u16x4*)(d0 + lane*4)       = u0;
        *(u16x4*)(d0 + 256 + lane*4) = u1;
        *(u16x4*)(d1 + lane*4)       = u2;
        *(u16x4*)(d1 + 256 + lane*4) = u3;
        #pragma unroll
        for (int dd = 1; dd < 64; dd <<= 1){
            ss0 += __shfl_xor(ss0, dd, 64);
            ss1 += __shfl_xor(ss1, dd, 64);
        }
        if (lane == 0){
            rnormS[buf][r0] = (ss0 > 0.f) ? (1.0f/sqrtf(ss0)) : 0.f;
            rnormS[buf][r1] = (ss1 > 0.f) ? (1.0f/sqrtf(ss1)) : 0.f;
        }
    };

    // prologue: tile 0 into buffer 0
    {
        float4 v[4];
        loadT(0, v);
        storeT(v, 0);
    }
    __syncthreads();

    for (int pt = 0; pt < 13; ++pt){
        const int cur = pt & 1, nxt = cur ^ 1;
        const bool hasNext = (pt < 12);

        float4 v[4];
        if (hasNext) loadT(pt + 1, v);   // prefetch: in flight under MFMA phase

        // ---- MFMA phase on buf[cur]: 16 ds_read shared by 2 MFMA chains ----
        const unsigned short* fbase = fT[cur] + col*520 + quad*8;
        f32x4 acc0 = {0.f,0.f,0.f,0.f};
        f32x4 acc1 = {0.f,0.f,0.f,0.f};
        #pragma unroll
        for (int j = 0; j < 16; ++j){
            bf16x8 a = *(const bf16x8*)(fbase + j*32);
            acc0 = __builtin_amdgcn_mfma_f32_16x16x32_bf16(a, B0[j], acc0, 0, 0, 0);
            acc1 = __builtin_amdgcn_mfma_f32_16x16x32_bf16(a, B1[j], acc1, 0, 0, 0);
        }
        f32x4 rn4 = *(const f32x4*)(&rnormS[cur][quad*4]);
        #pragma unroll
        for (int rr = 0; rr < 4; ++rr){
            int prow = pt*16 + quad*4 + rr;
            if (prow < HW){
                float s0 = acc0[rr] * rn4[rr];
                float s1 = acc1[rr] * rn4[rr];
                float w0 = sigm((s0 - F_EPS_POS) * F_INV_TAU);
                float w1 = sigm((s1 - F_EPS_POS) * F_INV_TAU);
                en0 += w0*s0; ed0 += w0;
                en1 += w1*s1; ed1 += w1;
                if (kg0 == n){ float wn = 1.f - sigm((s0 - F_EPS_NEG) * F_INV_TAU); hn0 += wn*s0; hd0 += wn; }
                if (kg1 == n){ float wn = 1.f - sigm((s1 - F_EPS_NEG) * F_INV_TAU); hn1 += wn*s1; hd1 += wn; }
            }
        }

        if (hasNext) storeT(v, nxt);
        __syncthreads();
    }

    // reduce across quads (rows live in quads; k identical per quad)
    en0 += __shfl_xor(en0, 16, 64); en0 += __shfl_xor(en0, 32, 64);
    ed0 += __shfl_xor(ed0, 16, 64); ed0 += __shfl_xor(ed0, 32, 64);
    en1 += __shfl_xor(en1, 16, 64); en1 += __shfl_xor(en1, 32, 64);
    ed1 += __shfl_xor(ed1, 16, 64); ed1 += __shfl_xor(ed1, 32, 64);
    hn0 += __shfl_xor(hn0, 16, 64); hn0 += __shfl_xor(hn0, 32, 64);
    hd0 += __shfl_xor(hd0, 16, 64); hd0 += __shfl_xor(hd0, 32, 64);
    hn1 += __shfl_xor(hn1, 16, 64); hn1 += __shfl_xor(hn1, 32, 64);
    hd1 += __shfl_xor(hd1, 16, 64); hd1 += __shfl_xor(hd1, 32, 64);

    if (quad == 0){
        num[n*N_IMG + kg0] = en0;  den[n*N_IMG + kg0] = ed0;
        num[n*N_IMG + kg1] = en1;  den[n*N_IMG + kg1] = ed1;
        if (kg0 == n){ hnum[n] = hn0; hden[n] = hd0; }
        if (kg1 == n){ hnum[n] = hn1; hden[n] = hd1; }
    }
}

// ---------------- kernel 3: per-n Pi_d / Ni_d (parallel over n) ----------------
__global__ void pd_k(const float* __restrict__ num, const float* __restrict__ den,
                     const float* __restrict__ hnum, const float* __restrict__ hden,
                     float* __restrict__ Pi_d, float* __restrict__ Ni_d){
    int nn = blockIdx.x, t = threadIdx.x;
    __shared__ float red[256];
    __shared__ float diagv;
    float ratio = num[nn*N_IMG + t] / den[nn*N_IMG + t];
    if (t == nn) diagv = ratio;
    red[t] = ratio * (t == nn ? -99.f : 1.f);
    __syncthreads();
    for (int s = 128; s > 0; s >>= 1){
        if (t < s) red[t] += red[t+s];
        __syncthreads();
    }
    if (t == 0){
        Pi_d[nn] = F_TEMP * diagv;
        Ni_d[nn] = F_TEMP * (hnum[nn]/hden[nn] + red[0]);
    }
}

// ---------------- kernel 4: broadcast (N,N) log-sum + atomic total ----------------
// loss = (1/N) * sum_{i,j} log(1 + exp(Ni_d[j] - Pi_d[i]))
__global__ void loss_k(const float* __restrict__ Pi_d, const float* __restrict__ Ni_d,
                       float* __restrict__ out){
    int i = blockIdx.x, j = threadIdx.x;
    __shared__ float red[256];
    float x = Ni_d[j] - Pi_d[i];
    red[j] = (x > 20.f) ? x : log1pf(__expf(x));
    __syncthreads();
    for (int s = 128; s > 0; s >>= 1){
        if (j < s) red[j] += red[j+s];
        __syncthreads();
    }
    if (j == 0) atomicAdd(out, red[0] * (1.0f/(float)N_IMG));
}

extern "C" void kernel_launch(void* const* d_in, const int* in_sizes, int n_in,
                              void* d_out, int out_size, void* d_ws, size_t ws_size,
                              hipStream_t stream) {
    const float* frame = (const float*)d_in[0];
    const float* audio = (const float*)d_in[1];
    float* out = (float*)d_out;
    char* ws = (char*)d_ws;

    unsigned short* abf = (unsigned short*)(ws);            // 262144 B
    float* num  = (float*)(ws + 262144);                    // 262144 B
    float* den  = (float*)(ws + 524288);                    // 262144 B
    float* hnum = (float*)(ws + 786432);                    // 1024 B
    float* hden = (float*)(ws + 787456);                    // 1024 B
    float* Pi_d = (float*)(ws + 788480);                    // 1024 B
    float* Ni_d = (float*)(ws + 789504);                    // 1024 B

    hipMemsetAsync(out, 0, sizeof(float), stream);          // capture-legal

    audio_norm_k<<<N_IMG, 256, 0, stream>>>(audio, abf);
    main_k<<<N_IMG, 512, 0, stream>>>(frame, abf, num, den, hnum, hden);
    pd_k<<<N_IMG, 256, 0, stream>>>(num, den, hnum, hden, Pi_d, Ni_d);
    loss_k<<<N_IMG, 256, 0, stream>>>(Pi_d, Ni_d, out);
}